// Round 1
// 740.602 us; speedup vs baseline: 1.1084x; 1.1084x over previous
//
#include <hip/hip_runtime.h>
#include <math.h>

static constexpr int S  = 2048;
static constexpr int D  = 64;
static constexpr int BH = 32;   // B*H = 2*16

typedef __bf16 bf16;
typedef __bf16 bf16x8 __attribute__((ext_vector_type(8)));
typedef float  f32x4  __attribute__((ext_vector_type(4)));

__device__ __forceinline__ int swz(int row, int chunk) { return chunk ^ (row & 7); }

__device__ __forceinline__ f32x4 mfma16(bf16x8 a, bf16x8 b, f32x4 c) {
    return __builtin_amdgcn_mfma_f32_16x16x32_bf16(a, b, c, 0, 0, 0);
}

// async global->LDS, 16B per lane; LDS dest is wave-uniform base + lane*16
__device__ __forceinline__ void gl16(const bf16* g, bf16* l) {
    __builtin_amdgcn_global_load_lds(
        (const __attribute__((address_space(1))) void*)g,
        (__attribute__((address_space(3))) void*)l,
        16, 0, 0);
}

// Stage a 64x64 fp32 tile (row-major, row stride 64) into LDS as bf16,
// row-major with XOR-swizzled 16B chunks: element (r,k) -> r*64 + (k>>3 ^ (r&7))*8 + (k&7)
__device__ __forceinline__ void stage_rowmajor(const float* __restrict__ src,
                                               bf16* dst, int tid) {
#pragma unroll
    for (int u = 0; u < 2; ++u) {
        const int id  = tid + u * 256;      // chunk id 0..511
        const int row = id >> 3;
        const int c   = id & 7;
        const float4* p = (const float4*)(src + row * 64 + c * 8);
        float4 a = p[0], b = p[1];
        bf16x8 v;
        v[0] = (bf16)a.x; v[1] = (bf16)a.y; v[2] = (bf16)a.z; v[3] = (bf16)a.w;
        v[4] = (bf16)b.x; v[5] = (bf16)b.y; v[6] = (bf16)b.z; v[7] = (bf16)b.w;
        *(bf16x8*)(dst + row * 64 + swz(row, c) * 8) = v;
    }
}

// ---------------------------------------------------------------------------
// P0a: bit-pack masks [2][S][S] int32 -> [2][S][S/32] u32 (1 MiB, L2-resident)
// ---------------------------------------------------------------------------
__global__ __launch_bounds__(256) void p0_bitpack(const int* __restrict__ masks,
                                                  unsigned* __restrict__ mbits) {
    const int idx = blockIdx.x * 256 + threadIdx.x;   // (b*S+s)*64 + w
    const int4* p = (const int4*)(masks + (size_t)idx * 32);
    unsigned word = 0;
#pragma unroll
    for (int i = 0; i < 8; ++i) {
        int4 m = p[i];
        word |= (m.x != 0 ? 1u : 0u) << (i * 4 + 0);
        word |= (m.y != 0 ? 1u : 0u) << (i * 4 + 1);
        word |= (m.z != 0 ? 1u : 0u) << (i * 4 + 2);
        word |= (m.w != 0 ? 1u : 0u) << (i * 4 + 3);
    }
    mbits[idx] = word;
}

// ---------------------------------------------------------------------------
// P0b: K -> bf16 tiled+swizzled image. One block per 64x64 tile (bh*32+kt).
// Image tile byte layout == the LDS tile layout, so staging is a linear copy.
// ---------------------------------------------------------------------------
__global__ __launch_bounds__(256) void p0_kimg(const float* __restrict__ src,
                                               bf16* __restrict__ img) {
    const int tile = blockIdx.x;            // bh*32 + kt
    const int tid  = threadIdx.x;
    const float* sbase = src + (size_t)tile * 4096;
    bf16* dbase = img + (size_t)tile * 4096;
#pragma unroll
    for (int u = 0; u < 2; ++u) {
        const int id  = tid + u * 256;
        const int row = id >> 3;
        const int c   = id & 7;
        const float4* p = (const float4*)(sbase + row * 64 + c * 8);
        float4 a = p[0], b = p[1];
        bf16x8 v;
        v[0] = (bf16)a.x; v[1] = (bf16)a.y; v[2] = (bf16)a.z; v[3] = (bf16)a.w;
        v[4] = (bf16)b.x; v[5] = (bf16)b.y; v[6] = (bf16)b.z; v[7] = (bf16)b.w;
        *(bf16x8*)(dbase + row * 64 + swz(row, c) * 8) = v;
    }
}

// ---------------------------------------------------------------------------
// P0c: V -> transposed bf16 tiled+swizzled image Vt[d][t] per tile.
// Transpose through padded LDS (pitch 65 f32: conflict-free column reads).
// Pays the transpose ONCE instead of per row-block (32x) in P1.
// ---------------------------------------------------------------------------
__global__ __launch_bounds__(256) void p0_vimg(const float* __restrict__ src,
                                               bf16* __restrict__ img) {
    __shared__ float Vf[64 * 65];
    const int tile = blockIdx.x;            // bh*32 + kt
    const int tid  = threadIdx.x;
    const float* sbase = src + (size_t)tile * 4096;
    bf16* dbase = img + (size_t)tile * 4096;
#pragma unroll
    for (int u = 0; u < 2; ++u) {
        const int id  = tid + u * 256;
        const int row = id >> 3;            // t
        const int c   = id & 7;
        const float4* p = (const float4*)(sbase + row * 64 + c * 8);
        float4 a = p[0], b = p[1];
        float* d = Vf + row * 65 + c * 8;
        d[0] = a.x; d[1] = a.y; d[2] = a.z; d[3] = a.w;
        d[4] = b.x; d[5] = b.y; d[6] = b.z; d[7] = b.w;
    }
    __syncthreads();
#pragma unroll
    for (int u = 0; u < 2; ++u) {
        const int id = tid + u * 256;
        const int dd = id >> 3;             // d
        const int c  = id & 7;              // t chunk
        bf16x8 v;
#pragma unroll
        for (int j = 0; j < 8; ++j) v[j] = (bf16)Vf[(c * 8 + j) * 65 + dd];
        *(bf16x8*)(dbase + dd * 64 + swz(dd, c) * 8) = v;
    }
}

// ---------------------------------------------------------------------------
// P1: out = (masked scaled scores) @ V   [MFMA, faithful bug: raw scores]
//     linv[row] = 1 / sum_t exp(score)
// One block per (bh, 64-row tile). 4 waves, each owns a 16-row strip.
// K/V tiles staged from bf16 images via global_load_lds, double-buffered:
// next tile's loads issued before current tile's compute (latency hidden).
// ---------------------------------------------------------------------------
__global__ __launch_bounds__(256) void p1_out_stats(
    const float* __restrict__ q, const bf16* __restrict__ Kimg,
    const bf16* __restrict__ Vimg, const unsigned* __restrict__ mbits,
    float* __restrict__ out, float* __restrict__ linv) {
    __shared__ __align__(16) bf16 Qs[64 * 64];
    __shared__ __align__(16) bf16 KB[2][64 * 64];
    __shared__ __align__(16) bf16 VB[2][64 * 64];
    __shared__ __align__(16) bf16 Sb[4][16 * 64];   // per-wave private strip

    const int bh   = blockIdx.x;
    const int s0   = blockIdx.y * 64;
    const int b    = bh >> 4;
    const int tid  = threadIdx.x;
    const int w    = tid >> 6;
    const int lane = tid & 63;
    const int col  = lane & 15;
    const int quad = lane >> 4;

    const bf16* kt_base = Kimg + (size_t)bh * 32 * 4096;
    const bf16* vt_base = Vimg + (size_t)bh * 32 * 4096;
    const int soff = w * 1024 + lane * 8;   // per-lane source element offset
    const int doff = w * 1024;              // wave-uniform LDS dest element offset

    stage_rowmajor(q + ((size_t)bh * S + s0) * D, Qs, tid);
    // prologue: stage tile 0 into buffer 0
    gl16(kt_base + soff,       &KB[0][doff]);
    gl16(kt_base + soff + 512, &KB[0][doff + 512]);
    gl16(vt_base + soff,       &VB[0][doff]);
    gl16(vt_base + soff + 512, &VB[0][doff + 512]);
    __syncthreads();   // drains vmcnt: Q + tile 0 resident

    const int ar = w * 16 + col;               // A-operand row (m = lane&15)
    bf16x8 aQ0 = *(bf16x8*)(Qs + ar * 64 + swz(ar, quad) * 8);
    bf16x8 aQ1 = *(bf16x8*)(Qs + ar * 64 + swz(ar, 4 + quad) * 8);

    f32x4 oacc[4] = {};
    float l[4] = {0.f, 0.f, 0.f, 0.f};

    const unsigned* mrow[4];
#pragma unroll
    for (int r = 0; r < 4; ++r)
        mrow[r] = mbits + (size_t)(b * S + s0 + w * 16 + quad * 4 + r) * 64;

    int cur = 0;
    for (int kt = 0; kt < 32; ++kt) {
        // mask loads FIRST (oldest-first vmcnt: their wait won't drain the stage)
        unsigned mw[4][2];
#pragma unroll
        for (int r = 0; r < 4; ++r) {
            mw[r][0] = mrow[r][kt * 2 + 0];
            mw[r][1] = mrow[r][kt * 2 + 1];
        }

        // prefetch next tile into the other buffer (overlaps with compute below)
        if (kt < 31) {
            const bf16* ks = kt_base + (size_t)(kt + 1) * 4096 + soff;
            const bf16* vs = vt_base + (size_t)(kt + 1) * 4096 + soff;
            bf16* kd = &KB[cur ^ 1][doff];
            bf16* vd = &VB[cur ^ 1][doff];
            gl16(ks,       kd);
            gl16(ks + 512, kd + 512);
            gl16(vs,       vd);
            gl16(vs + 512, vd + 512);
        }

        const bf16* Kc = KB[cur];
        const bf16* Vc = VB[cur];

        // ---- QK^T, mask+scale, exp-sum, stash S (bf16) in A-layout strip ----
#pragma unroll
        for (int ct = 0; ct < 4; ++ct) {
            const int br = ct * 16 + col;      // K row (t)
            bf16x8 b0 = *(bf16x8*)(Kc + br * 64 + swz(br, quad) * 8);
            bf16x8 b1 = *(bf16x8*)(Kc + br * 64 + swz(br, 4 + quad) * 8);
            f32x4 s = {};
            s = mfma16(aQ0, b0, s);
            s = mfma16(aQ1, b1, s);
            const int t   = ct * 16 + col;
            const int pos = t & 31;
#pragma unroll
            for (int r = 0; r < 4; ++r) {
                const float sv = ((mw[r][ct >> 1] >> pos) & 1u)
                                     ? s[r] * 0.125f : -1e-12f;
                l[r] += __expf(sv);
                const int sr = quad * 4 + r;   // C-layout row within strip
                Sb[w][sr * 64 + swz(sr, t >> 3) * 8 + (t & 7)] = (bf16)sv;
            }
        }

        // ---- out += S @ V (wave-private strip, no barrier needed) ----
        bf16x8 aS0 = *(bf16x8*)(&Sb[w][col * 64 + swz(col, quad) * 8]);
        bf16x8 aS1 = *(bf16x8*)(&Sb[w][col * 64 + swz(col, 4 + quad) * 8]);
#pragma unroll
        for (int dt = 0; dt < 4; ++dt) {
            const int vr = dt * 16 + col;      // Vt row (d)
            bf16x8 b0 = *(bf16x8*)(Vc + vr * 64 + swz(vr, quad) * 8);
            bf16x8 b1 = *(bf16x8*)(Vc + vr * 64 + swz(vr, 4 + quad) * 8);
            oacc[dt] = mfma16(aS0, b0, oacc[dt]);
            oacc[dt] = mfma16(aS1, b1, oacc[dt]);
        }

        __syncthreads();   // drains vmcnt: next tile resident; all waves done reading cur
        cur ^= 1;
    }

    // ---- epilogue: out rows (s0 + w*16 + quad*4 + r), cols (dt*16 + col) ----
    float* ob = out + ((size_t)bh * S + s0 + w * 16 + quad * 4) * D;
#pragma unroll
    for (int dt = 0; dt < 4; ++dt)
#pragma unroll
        for (int r = 0; r < 4; ++r)
            ob[(size_t)r * D + dt * 16 + col] = oacc[dt][r];

#pragma unroll
    for (int r = 0; r < 4; ++r) {
        float x = l[r];
        x += __shfl_xor(x, 1, 16);
        x += __shfl_xor(x, 2, 16);
        x += __shfl_xor(x, 4, 16);
        x += __shfl_xor(x, 8, 16);
        if (col == 0)
            linv[(size_t)bh * S + s0 + w * 16 + quad * 4 + r] = 1.0f / x;
    }
}

// ---------------------------------------------------------------------------
// P2: recompute scores, write attn = exp(score) * linv[row]  (512 MiB stream)
// K staged from bf16 image, double-buffered like P1.
// ---------------------------------------------------------------------------
__global__ __launch_bounds__(256) void p2_attn(
    const float* __restrict__ q, const bf16* __restrict__ Kimg,
    const unsigned* __restrict__ mbits, const float* __restrict__ linv,
    float* __restrict__ attn) {
    __shared__ __align__(16) bf16 Qs[64 * 64];
    __shared__ __align__(16) bf16 KB[2][64 * 64];

    const int bh   = blockIdx.x;
    const int s0   = blockIdx.y * 64;
    const int b    = bh >> 4;
    const int tid  = threadIdx.x;
    const int w    = tid >> 6;
    const int lane = tid & 63;
    const int col  = lane & 15;
    const int quad = lane >> 4;

    const bf16* kt_base = Kimg + (size_t)bh * 32 * 4096;
    const int soff = w * 1024 + lane * 8;
    const int doff = w * 1024;

    stage_rowmajor(q + ((size_t)bh * S + s0) * D, Qs, tid);
    gl16(kt_base + soff,       &KB[0][doff]);
    gl16(kt_base + soff + 512, &KB[0][doff + 512]);
    __syncthreads();

    const int ar = w * 16 + col;
    bf16x8 aQ0 = *(bf16x8*)(Qs + ar * 64 + swz(ar, quad) * 8);
    bf16x8 aQ1 = *(bf16x8*)(Qs + ar * 64 + swz(ar, 4 + quad) * 8);

    float li[4];
    const unsigned* mrow[4];
#pragma unroll
    for (int r = 0; r < 4; ++r) {
        const int srow = s0 + w * 16 + quad * 4 + r;
        li[r]   = linv[(size_t)bh * S + srow];
        mrow[r] = mbits + (size_t)(b * S + srow) * 64;
    }

    float* ab = attn + ((size_t)bh * S + s0 + w * 16 + quad * 4) * (size_t)S;

    int cur = 0;
    for (int kt = 0; kt < 32; ++kt) {
        unsigned mw[4][2];
#pragma unroll
        for (int r = 0; r < 4; ++r) {
            mw[r][0] = mrow[r][kt * 2 + 0];
            mw[r][1] = mrow[r][kt * 2 + 1];
        }

        if (kt < 31) {
            const bf16* ks = kt_base + (size_t)(kt + 1) * 4096 + soff;
            bf16* kd = &KB[cur ^ 1][doff];
            gl16(ks,       kd);
            gl16(ks + 512, kd + 512);
        }

        const bf16* Kc = KB[cur];

#pragma unroll
        for (int ct = 0; ct < 4; ++ct) {
            const int br = ct * 16 + col;
            bf16x8 b0 = *(bf16x8*)(Kc + br * 64 + swz(br, quad) * 8);
            bf16x8 b1 = *(bf16x8*)(Kc + br * 64 + swz(br, 4 + quad) * 8);
            f32x4 s = {};
            s = mfma16(aQ0, b0, s);
            s = mfma16(aQ1, b1, s);
            const int t   = ct * 16 + col;
            const int pos = t & 31;
#pragma unroll
            for (int r = 0; r < 4; ++r) {
                const float sv = ((mw[r][ct >> 1] >> pos) & 1u)
                                     ? s[r] * 0.125f : -1e-12f;
                ab[(size_t)r * S + kt * 64 + t] = __expf(sv) * li[r];
            }
        }

        __syncthreads();
        cur ^= 1;
    }
}

extern "C" void kernel_launch(void* const* d_in, const int* in_sizes, int n_in,
                              void* d_out, int out_size, void* d_ws, size_t ws_size,
                              hipStream_t stream) {
    const float* q     = (const float*)d_in[0];
    const float* k     = (const float*)d_in[1];
    const float* v     = (const float*)d_in[2];
    const int*   masks = (const int*)d_in[3];

    float* out  = (float*)d_out;                 // [2,16,S,D]
    float* attn = out + (size_t)BH * S * D;      // [2,16,S,S]

    // workspace layout (17.25 MiB):
    //   [0, 1 MiB)            mbits
    //   [1 MiB, +256 KiB)     linv
    //   [1.25 MiB, +8 MiB)    Kimg  (bf16 tiled+swizzled)
    //   [9.25 MiB, +8 MiB)    Vimg  (bf16 transposed tiled+swizzled)
    unsigned* mbits = (unsigned*)d_ws;
    float*    linvp = (float*)((char*)d_ws + (size_t)1048576);
    bf16*     Kimg  = (bf16*)((char*)d_ws + (size_t)1048576 + 262144);
    bf16*     Vimg  = (bf16*)((char*)d_ws + (size_t)1048576 + 262144 + 8388608);

    p0_bitpack<<<(2 * S * 64) / 256, 256, 0, stream>>>(masks, mbits);
    p0_kimg<<<BH * 32, 256, 0, stream>>>(k, Kimg);
    p0_vimg<<<BH * 32, 256, 0, stream>>>(v, Vimg);

    dim3 g(BH, S / 64);   // x = bh (XCD round-robin keeps per-XCD K/Q hot set small)
    p1_out_stats<<<g, 256, 0, stream>>>(q, Kimg, Vimg, mbits, out, linvp);
    p2_attn<<<g, 256, 0, stream>>>(q, Kimg, mbits, linvp, attn);
}

// Round 2
// 718.100 us; speedup vs baseline: 1.1431x; 1.0313x over previous
//
#include <hip/hip_runtime.h>
#include <math.h>

static constexpr int S  = 2048;
static constexpr int D  = 64;
static constexpr int BH = 32;   // B*H = 2*16

typedef __bf16 bf16;
typedef __bf16 bf16x8 __attribute__((ext_vector_type(8)));
typedef float  f32x4  __attribute__((ext_vector_type(4)));

__device__ __forceinline__ int swz(int row, int chunk) { return chunk ^ (row & 7); }

__device__ __forceinline__ f32x4 mfma16(bf16x8 a, bf16x8 b, f32x4 c) {
    return __builtin_amdgcn_mfma_f32_16x16x32_bf16(a, b, c, 0, 0, 0);
}

// async global->LDS, 16B per lane; LDS dest is wave-uniform base + lane*16
__device__ __forceinline__ void gl16(const bf16* g, bf16* l) {
    __builtin_amdgcn_global_load_lds(
        (const __attribute__((address_space(1))) void*)g,
        (__attribute__((address_space(3))) void*)l,
        16, 0, 0);
}

// Stage a Rx64 fp32 tile (row-major, row stride 64) into LDS as bf16,
// row-major with XOR-swizzled 16B chunks: element (r,k) -> r*64 + (k>>3 ^ (r&7))*8 + (k&7)
// NTHREADS threads stage R*8 chunks (R*64 elements), 2 chunks per thread when R==NTHREADS/4.
template <int NCHUNK>
__device__ __forceinline__ void stage_rowmajor(const float* __restrict__ src,
                                               bf16* dst, int tid, int nthreads) {
#pragma unroll
    for (int id = tid; id < NCHUNK; id += 512) {
        const int row = id >> 3;
        const int c   = id & 7;
        const float4* p = (const float4*)(src + row * 64 + c * 8);
        float4 a = p[0], b = p[1];
        bf16x8 v;
        v[0] = (bf16)a.x; v[1] = (bf16)a.y; v[2] = (bf16)a.z; v[3] = (bf16)a.w;
        v[4] = (bf16)b.x; v[5] = (bf16)b.y; v[6] = (bf16)b.z; v[7] = (bf16)b.w;
        *(bf16x8*)(dst + row * 64 + swz(row, c) * 8) = v;
    }
}

// ---------------------------------------------------------------------------
// P0a: bit-pack masks [2][S][S] int32 -> [2][S][S/32] u32 (1 MiB, L2-resident)
// ---------------------------------------------------------------------------
__global__ __launch_bounds__(256) void p0_bitpack(const int* __restrict__ masks,
                                                  unsigned* __restrict__ mbits) {
    const int idx = blockIdx.x * 256 + threadIdx.x;   // (b*S+s)*64 + w
    const int4* p = (const int4*)(masks + (size_t)idx * 32);
    unsigned word = 0;
#pragma unroll
    for (int i = 0; i < 8; ++i) {
        int4 m = p[i];
        word |= (m.x != 0 ? 1u : 0u) << (i * 4 + 0);
        word |= (m.y != 0 ? 1u : 0u) << (i * 4 + 1);
        word |= (m.z != 0 ? 1u : 0u) << (i * 4 + 2);
        word |= (m.w != 0 ? 1u : 0u) << (i * 4 + 3);
    }
    mbits[idx] = word;
}

// ---------------------------------------------------------------------------
// P0b: K -> bf16 tiled+swizzled image; V -> transposed bf16 tiled+swizzled
// image Vt[d][t]. One block per 64x64 tile; blocks [0,1024) do K, [1024,2048) V.
// Image tile byte layout == the LDS tile layout, so P1/P2 staging is a linear
// copy, and the V transpose is paid ONCE (not per row-block).
// ---------------------------------------------------------------------------
__global__ __launch_bounds__(256) void p0_kvimg(const float* __restrict__ ksrc,
                                                const float* __restrict__ vsrc,
                                                bf16* __restrict__ kimg,
                                                bf16* __restrict__ vimg) {
    __shared__ float Vf[64 * 65];
    const int tid = threadIdx.x;
    if (blockIdx.x < 1024) {                       // ---- K path ----
        const int tile = blockIdx.x;
        const float* sbase = ksrc + (size_t)tile * 4096;
        bf16* dbase = kimg + (size_t)tile * 4096;
#pragma unroll
        for (int u = 0; u < 2; ++u) {
            const int id  = tid + u * 256;
            const int row = id >> 3;
            const int c   = id & 7;
            const float4* p = (const float4*)(sbase + row * 64 + c * 8);
            float4 a = p[0], b = p[1];
            bf16x8 v;
            v[0] = (bf16)a.x; v[1] = (bf16)a.y; v[2] = (bf16)a.z; v[3] = (bf16)a.w;
            v[4] = (bf16)b.x; v[5] = (bf16)b.y; v[6] = (bf16)b.z; v[7] = (bf16)b.w;
            *(bf16x8*)(dbase + row * 64 + swz(row, c) * 8) = v;
        }
    } else {                                       // ---- V transpose path ----
        const int tile = blockIdx.x - 1024;
        const float* sbase = vsrc + (size_t)tile * 4096;
        bf16* dbase = vimg + (size_t)tile * 4096;
#pragma unroll
        for (int u = 0; u < 2; ++u) {
            const int id  = tid + u * 256;
            const int row = id >> 3;            // t
            const int c   = id & 7;
            const float4* p = (const float4*)(sbase + row * 64 + c * 8);
            float4 a = p[0], b = p[1];
            float* d = Vf + row * 65 + c * 8;
            d[0] = a.x; d[1] = a.y; d[2] = a.z; d[3] = a.w;
            d[4] = b.x; d[5] = b.y; d[6] = b.z; d[7] = b.w;
        }
        __syncthreads();
#pragma unroll
        for (int u = 0; u < 2; ++u) {
            const int id = tid + u * 256;
            const int dd = id >> 3;             // d
            const int c  = id & 7;              // t chunk
            bf16x8 v;
#pragma unroll
            for (int j = 0; j < 8; ++j) v[j] = (bf16)Vf[(c * 8 + j) * 65 + dd];
            *(bf16x8*)(dbase + dd * 64 + swz(dd, c) * 8) = v;
        }
    }
}

// ---------------------------------------------------------------------------
// P1: out = (masked scaled scores) @ V   [MFMA, faithful bug: raw scores]
//     linv[row] = 1 / sum_t exp(score)
// 512 threads = 8 waves, 128 Q-rows per block (wave w owns rows w*16..w*16+15).
// K/V double-buffered via global_load_lds from pre-swizzled bf16 images.
// Qs LDS is reused as the per-wave S strip after aQ moves to registers
// (keeps LDS at 48 KiB -> 2 blocks/CU resident = 4 waves/SIMD).
// ---------------------------------------------------------------------------
__global__ __launch_bounds__(512) void p1_out_stats(
    const float* __restrict__ q, const bf16* __restrict__ Kimg,
    const bf16* __restrict__ Vimg, const unsigned* __restrict__ mbits,
    float* __restrict__ out, float* __restrict__ linv) {
    __shared__ __align__(16) bf16 QSb[128 * 64];   // Q (prologue) -> Sb[8][16*64]
    __shared__ __align__(16) bf16 KB[2][64 * 64];
    __shared__ __align__(16) bf16 VB[2][64 * 64];

    const int bh   = blockIdx.y;
    const int s0   = blockIdx.x * 128;
    const int b    = bh >> 4;
    const int tid  = threadIdx.x;
    const int w    = tid >> 6;
    const int lane = tid & 63;
    const int col  = lane & 15;
    const int quad = lane >> 4;

    const bf16* kt_base = Kimg + (size_t)bh * 32 * 4096;
    const bf16* vt_base = Vimg + (size_t)bh * 32 * 4096;
    const int soff = tid * 8;          // per-lane source element offset (16B/lane)
    const int doff = w * 512;          // wave-uniform LDS dest element offset

    stage_rowmajor<1024>(q + ((size_t)bh * S + s0) * D, QSb, tid, 512);
    // prologue: stage tile 0 into buffer 0 (1 KiB per wave per operand)
    gl16(kt_base + soff, &KB[0][doff]);
    gl16(vt_base + soff, &VB[0][doff]);
    __syncthreads();   // Q + tile 0 resident

    const int ar = w * 16 + col;               // A-operand row (m = lane&15)
    bf16x8 aQ0 = *(bf16x8*)(QSb + ar * 64 + swz(ar, quad) * 8);
    bf16x8 aQ1 = *(bf16x8*)(QSb + ar * 64 + swz(ar, 4 + quad) * 8);
    __syncthreads();   // all waves hold aQ in regs; QSb now reusable as Sb

    bf16* Sbw = QSb + w * 1024;        // wave-private 16x64 strip

    f32x4 oacc[4] = {};
    float l[4] = {0.f, 0.f, 0.f, 0.f};

    const unsigned* mrow[4];
#pragma unroll
    for (int r = 0; r < 4; ++r)
        mrow[r] = mbits + (size_t)(b * S + s0 + w * 16 + quad * 4 + r) * 64;

    int cur = 0;
    for (int kt = 0; kt < 32; ++kt) {
        // mask loads FIRST (oldest-first vmcnt: their wait won't drain the stage)
        unsigned mw[4][2];
#pragma unroll
        for (int r = 0; r < 4; ++r) {
            mw[r][0] = mrow[r][kt * 2 + 0];
            mw[r][1] = mrow[r][kt * 2 + 1];
        }

        // prefetch next tile into the other buffer (overlaps with compute below)
        if (kt < 31) {
            gl16(kt_base + (size_t)(kt + 1) * 4096 + soff, &KB[cur ^ 1][doff]);
            gl16(vt_base + (size_t)(kt + 1) * 4096 + soff, &VB[cur ^ 1][doff]);
        }

        const bf16* Kc = KB[cur];
        const bf16* Vc = VB[cur];

        // ---- QK^T, mask+scale, exp-sum, stash S (bf16) in A-layout strip ----
#pragma unroll
        for (int ct = 0; ct < 4; ++ct) {
            const int br = ct * 16 + col;      // K row (t)
            bf16x8 b0 = *(bf16x8*)(Kc + br * 64 + swz(br, quad) * 8);
            bf16x8 b1 = *(bf16x8*)(Kc + br * 64 + swz(br, 4 + quad) * 8);
            __builtin_amdgcn_s_setprio(1);
            f32x4 s = {};
            s = mfma16(aQ0, b0, s);
            s = mfma16(aQ1, b1, s);
            __builtin_amdgcn_s_setprio(0);
            const int t   = ct * 16 + col;
            const int pos = t & 31;
#pragma unroll
            for (int r = 0; r < 4; ++r) {
                const float sv = ((mw[r][ct >> 1] >> pos) & 1u)
                                     ? s[r] * 0.125f : -1e-12f;
                l[r] += __expf(sv);
                const int sr = quad * 4 + r;   // C-layout row within strip
                Sbw[sr * 64 + swz(sr, t >> 3) * 8 + (t & 7)] = (bf16)sv;
            }
        }

        // ---- out += S @ V (wave-private strip, no barrier needed) ----
        bf16x8 aS0 = *(bf16x8*)(Sbw + col * 64 + swz(col, quad) * 8);
        bf16x8 aS1 = *(bf16x8*)(Sbw + col * 64 + swz(col, 4 + quad) * 8);
        __builtin_amdgcn_s_setprio(1);
#pragma unroll
        for (int dt = 0; dt < 4; ++dt) {
            const int vr = dt * 16 + col;      // Vt row (d)
            bf16x8 b0 = *(bf16x8*)(Vc + vr * 64 + swz(vr, quad) * 8);
            bf16x8 b1 = *(bf16x8*)(Vc + vr * 64 + swz(vr, 4 + quad) * 8);
            oacc[dt] = mfma16(aS0, b0, oacc[dt]);
            oacc[dt] = mfma16(aS1, b1, oacc[dt]);
        }
        __builtin_amdgcn_s_setprio(0);

        __syncthreads();   // next tile resident; all waves done reading cur
        cur ^= 1;
    }

    // ---- epilogue: out rows (s0 + w*16 + quad*4 + r), cols (dt*16 + col) ----
    float* ob = out + ((size_t)bh * S + s0 + w * 16 + quad * 4) * D;
#pragma unroll
    for (int dt = 0; dt < 4; ++dt)
#pragma unroll
        for (int r = 0; r < 4; ++r)
            ob[(size_t)r * D + dt * 16 + col] = oacc[dt][r];

#pragma unroll
    for (int r = 0; r < 4; ++r) {
        float x = l[r];
        x += __shfl_xor(x, 1, 16);
        x += __shfl_xor(x, 2, 16);
        x += __shfl_xor(x, 4, 16);
        x += __shfl_xor(x, 8, 16);
        if (col == 0)
            linv[(size_t)bh * S + s0 + w * 16 + quad * 4 + r] = 1.0f / x;
    }
}

// ---------------------------------------------------------------------------
// P2: recompute scores, write attn = exp(score) * linv[row]  (512 MiB stream)
// 512 threads, 128 rows/block; K staged from bf16 image, double-buffered.
// ---------------------------------------------------------------------------
__global__ __launch_bounds__(512) void p2_attn(
    const float* __restrict__ q, const bf16* __restrict__ Kimg,
    const unsigned* __restrict__ mbits, const float* __restrict__ linv,
    float* __restrict__ attn) {
    __shared__ __align__(16) bf16 Qs[128 * 64];
    __shared__ __align__(16) bf16 KB[2][64 * 64];

    const int bh   = blockIdx.y;
    const int s0   = blockIdx.x * 128;
    const int b    = bh >> 4;
    const int tid  = threadIdx.x;
    const int w    = tid >> 6;
    const int lane = tid & 63;
    const int col  = lane & 15;
    const int quad = lane >> 4;

    const bf16* kt_base = Kimg + (size_t)bh * 32 * 4096;
    const int soff = tid * 8;
    const int doff = w * 512;

    stage_rowmajor<1024>(q + ((size_t)bh * S + s0) * D, Qs, tid, 512);
    gl16(kt_base + soff, &KB[0][doff]);
    __syncthreads();

    const int ar = w * 16 + col;
    bf16x8 aQ0 = *(bf16x8*)(Qs + ar * 64 + swz(ar, quad) * 8);
    bf16x8 aQ1 = *(bf16x8*)(Qs + ar * 64 + swz(ar, 4 + quad) * 8);

    float li[4];
    const unsigned* mrow[4];
#pragma unroll
    for (int r = 0; r < 4; ++r) {
        const int srow = s0 + w * 16 + quad * 4 + r;
        li[r]   = linv[(size_t)bh * S + srow];
        mrow[r] = mbits + (size_t)(b * S + srow) * 64;
    }

    float* ab = attn + ((size_t)bh * S + s0 + w * 16 + quad * 4) * (size_t)S;

    int cur = 0;
    for (int kt = 0; kt < 32; ++kt) {
        unsigned mw[4][2];
#pragma unroll
        for (int r = 0; r < 4; ++r) {
            mw[r][0] = mrow[r][kt * 2 + 0];
            mw[r][1] = mrow[r][kt * 2 + 1];
        }

        if (kt < 31)
            gl16(kt_base + (size_t)(kt + 1) * 4096 + soff, &KB[cur ^ 1][doff]);

        const bf16* Kc = KB[cur];

#pragma unroll
        for (int ct = 0; ct < 4; ++ct) {
            const int br = ct * 16 + col;
            bf16x8 b0 = *(bf16x8*)(Kc + br * 64 + swz(br, quad) * 8);
            bf16x8 b1 = *(bf16x8*)(Kc + br * 64 + swz(br, 4 + quad) * 8);
            __builtin_amdgcn_s_setprio(1);
            f32x4 s = {};
            s = mfma16(aQ0, b0, s);
            s = mfma16(aQ1, b1, s);
            __builtin_amdgcn_s_setprio(0);
            const int t   = ct * 16 + col;
            const int pos = t & 31;
#pragma unroll
            for (int r = 0; r < 4; ++r) {
                const float sv = ((mw[r][ct >> 1] >> pos) & 1u)
                                     ? s[r] * 0.125f : -1e-12f;
                ab[(size_t)r * S + kt * 64 + t] = __expf(sv) * li[r];
            }
        }

        __syncthreads();
        cur ^= 1;
    }
}

extern "C" void kernel_launch(void* const* d_in, const int* in_sizes, int n_in,
                              void* d_out, int out_size, void* d_ws, size_t ws_size,
                              hipStream_t stream) {
    const float* q     = (const float*)d_in[0];
    const float* k     = (const float*)d_in[1];
    const float* v     = (const float*)d_in[2];
    const int*   masks = (const int*)d_in[3];

    float* out  = (float*)d_out;                 // [2,16,S,D]
    float* attn = out + (size_t)BH * S * D;      // [2,16,S,S]

    // workspace layout (17.25 MiB):
    //   [0, 1 MiB)            mbits
    //   [1 MiB, +256 KiB)     linv
    //   [1.25 MiB, +8 MiB)    Kimg  (bf16 tiled+swizzled)
    //   [9.25 MiB, +8 MiB)    Vimg  (bf16 transposed tiled+swizzled)
    unsigned* mbits = (unsigned*)d_ws;
    float*    linvp = (float*)((char*)d_ws + (size_t)1048576);
    bf16*     Kimg  = (bf16*)((char*)d_ws + (size_t)1048576 + 262144);
    bf16*     Vimg  = (bf16*)((char*)d_ws + (size_t)1048576 + 262144 + 8388608);

    p0_bitpack<<<(2 * S * 64) / 256, 256, 0, stream>>>(masks, mbits);
    p0_kvimg<<<2048, 256, 0, stream>>>(k, v, Kimg, Vimg);

    dim3 g(S / 128, BH);   // x = row-tile (consecutive blocks share bh -> L2 locality)
    p1_out_stats<<<g, 512, 0, stream>>>(q, Kimg, Vimg, mbits, out, linvp);
    p2_attn<<<g, 512, 0, stream>>>(q, Kimg, mbits, linvp, attn);
}